// Round 2
// baseline (467.099 us; speedup 1.0000x reference)
//
#include <hip/hip_runtime.h>

typedef unsigned short u16;
typedef short bf16x8 __attribute__((ext_vector_type(8)));
typedef float f32x4 __attribute__((ext_vector_type(4)));

__device__ __forceinline__ float b2f(u16 u) { return __uint_as_float(((unsigned)u) << 16); }
__device__ __forceinline__ u16 f2bf(float f) {
  unsigned u = __float_as_uint(f);
  u += 0x7fffu + ((u >> 16) & 1u);   // RNE
  return (u16)(u >> 16);
}

// dual-dtype scalar load: input tensor is bf16 (u16) if isbf else f32
__device__ __forceinline__ float ldf(const void* p, int i, bool isbf) {
  return isbf ? b2f(((const u16*)p)[i]) : ((const float*)p)[i];
}
// dual-dtype 8-element load -> bf16 LDS
__device__ __forceinline__ void ld8(u16* dst, const void* p, int i, bool isbf) {
  if (isbf) {
    *(uint4*)dst = *(const uint4*)((const u16*)p + i);
  } else {
    float4 a = *(const float4*)((const float*)p + i);
    float4 b = *(const float4*)((const float*)p + i + 4);
    dst[0] = f2bf(a.x); dst[1] = f2bf(a.y); dst[2] = f2bf(a.z); dst[3] = f2bf(a.w);
    dst[4] = f2bf(b.x); dst[5] = f2bf(b.y); dst[6] = f2bf(b.z); dst[7] = f2bf(b.w);
  }
}

#define MFMA16(a, b, c) __builtin_amdgcn_mfma_f32_16x16x32_bf16((a), (b), (c), 0, 0, 0)

// ---------------------------------------------------------------------------
// dtype detector: classify hidden_states as bf16 vs f32 by exponent plausibility
// of the first 4096 u16 words. bf16 N(0,1): ~99.9% in-band. f32-as-u16: ~53%.
// ---------------------------------------------------------------------------
__global__ __launch_bounds__(256) void detect_kernel(const u16* __restrict__ h, int* __restrict__ flag) {
  int tid = threadIdx.x;
  int cnt = 0;
  for (int i = tid; i < 4096; i += 256) {
    int e = (h[i] >> 7) & 0xFF;
    cnt += (e >= 116 && e <= 132) ? 1 : 0;   // |x| in [2^-11, 2^5]
  }
  __shared__ int sh[256];
  sh[tid] = cnt; __syncthreads();
  for (int s = 128; s > 0; s >>= 1) { if (tid < s) sh[tid] += sh[tid + s]; __syncthreads(); }
  if (tid == 0) flag[0] = (sh[0] >= 3100) ? 1 : 0;
}

// ---------------------------------------------------------------------------
// cos/sin table: ctab[t][dm], t in [0,4032), dm in [0,64). float2 = (cos, sin)
// ---------------------------------------------------------------------------
__global__ __launch_bounds__(256) void ctab_kernel(float2* __restrict__ ctab) {
  int idx = blockIdx.x * 256 + threadIdx.x;       // 258048 exact
  int dm = idx & 63, t = idx >> 6;
  float f = exp2f(-(float)dm * (13.287712379549449f / 64.0f));
  float ang = (float)t * f;
  float s, c;
  sincosf(ang, &s, &c);
  ctab[idx] = make_float2(c, s);
}

// ---------------------------------------------------------------------------
// Tall-skinny projection: out[64][Ntot] = X[64][4096] . W[Ntot][4096]^T
// ---------------------------------------------------------------------------
__global__ __launch_bounds__(256) void proj_kernel(
    const void* __restrict__ X, const void* __restrict__ Wa,
    const void* __restrict__ Wb, const void* __restrict__ Wc,
    void* __restrict__ out, int Na, int Nb, int ostride,
    const int* __restrict__ flagp, int x_dyn, int out_dyn)
{
  bool fbf = (*flagp != 0);
  bool xbf = x_dyn ? fbf : true;
  int n0 = blockIdx.x * 16;
  const void* W; int wr0;
  if (n0 < Na)           { W = Wa; wr0 = n0; }
  else if (n0 < Na + Nb) { W = Wb; wr0 = n0 - Na; }
  else                   { W = Wc; wr0 = n0 - Na - Nb; }

  __shared__ u16 Xs[64][136];
  __shared__ u16 Ws[16][136];
  int tid = threadIdx.x;
  int wv = tid >> 6, lane = tid & 63, lr = lane & 15, lq = lane >> 4;
  f32x4 acc = {0.f, 0.f, 0.f, 0.f};

  for (int k0 = 0; k0 < 4096; k0 += 128) {
    __syncthreads();
    for (int u = tid; u < 1024; u += 256) {       // X tile 64x128
      int row = u >> 4, c8 = u & 15;
      ld8(&Xs[row][c8 * 8], X, row * 4096 + k0 + c8 * 8, xbf);
    }
    { int row = tid >> 4, c8 = tid & 15;          // W tile 16x128
      ld8(&Ws[row][c8 * 8], W, (wr0 + row) * 4096 + k0 + c8 * 8, fbf); }
    __syncthreads();
    for (int ks = 0; ks < 4; ks++) {
      bf16x8 af  = *(const bf16x8*)&Xs[wv * 16 + lr][ks * 32 + lq * 8];
      bf16x8 bfr = *(const bf16x8*)&Ws[lr][ks * 32 + lq * 8];
      acc = MFMA16(af, bfr, acc);
    }
  }
  for (int r = 0; r < 4; r++) {
    int idx = (wv * 16 + lq * 4 + r) * ostride + n0 + lr;
    if (out_dyn && !fbf) ((float*)out)[idx] = acc[r];
    else                 ((u16*)out)[idx]   = f2bf(acc[r]);
  }
}

// ---------------------------------------------------------------------------
// Prep: RoPE'd Q [bh][32][128], RoPE'd full-K [bh][64][128], V_full^T [bh][128][64]
// ---------------------------------------------------------------------------
__global__ __launch_bounds__(256) void prep_kernel(
    const u16* __restrict__ Cqkv, const void* __restrict__ kfp, const void* __restrict__ vfp,
    const float2* __restrict__ ctab, const int* __restrict__ flagp,
    u16* __restrict__ qrb, u16* __restrict__ kfullb, u16* __restrict__ vfullT)
{
  bool isbf = (*flagp != 0);
  int idx = blockIdx.x * 256 + threadIdx.x;       // 1,310,720 exact
  if (idx < 262144) {                              // qr
    int d = idx & 127, row = (idx >> 7) & 31, bh = idx >> 12;
    int b = bh >> 3, kvh = bh & 7, g = row >> 3, qp = row & 7;
    int tok = b * 8 + qp, h = kvh * 4 + g;
    float x  = b2f(Cqkv[tok * 6144 + h * 128 + d]);
    float x2 = b2f(Cqkv[tok * 6144 + h * 128 + (d ^ 64)]);
    float2 cs = ctab[(4024 + qp) * 64 + (d & 63)];
    float sgn = (d < 64) ? -1.f : 1.f;
    qrb[idx] = f2bf(x * cs.x + sgn * (x2 * cs.y));
  } else if (idx < 786432) {                       // k_full roped, pos = 3968+t
    int j = idx - 262144;
    int d = j & 127, t = (j >> 7) & 63, bh = j >> 13;
    int b = bh >> 3, kvh = bh & 7;
    float x, x2;
    if (t < 56) {
      x  = ldf(kfp, (bh * 56 + t) * 128 + d, isbf);
      x2 = ldf(kfp, (bh * 56 + t) * 128 + (d ^ 64), isbf);
    } else {
      int tok = b * 8 + (t - 56);
      x  = b2f(Cqkv[tok * 6144 + 4096 + kvh * 128 + d]);
      x2 = b2f(Cqkv[tok * 6144 + 4096 + kvh * 128 + (d ^ 64)]);
    }
    float2 cs = ctab[(3968 + t) * 64 + (d & 63)];
    float sgn = (d < 64) ? -1.f : 1.f;
    kfullb[j] = f2bf(x * cs.x + sgn * (x2 * cs.y));
  } else {                                         // v_full transposed [bh][d][t]
    int j = idx - 786432;
    int t = j & 63, d = (j >> 6) & 127, bh = j >> 13;
    int b = bh >> 3, kvh = bh & 7;
    float x;
    if (t < 56) x = ldf(vfp, (bh * 56 + t) * 128 + d, isbf);
    else        x = b2f(Cqkv[(b * 8 + t - 56) * 6144 + 5120 + kvh * 128 + d]);
    vfullT[j] = f2bf(x);
  }
}

// ---------------------------------------------------------------------------
// Online-flash attention over 8-chunk groups. Grid (64 bh, 4 grp).
// Chunks 0..30: 128 quantized keys (dequant+RoPE). Chunk 31: 64 full keys.
// Running (m, l, O) kept online within block; 4 partials merged by combine.
// ---------------------------------------------------------------------------
__global__ __launch_bounds__(256) void attn_kernel(
    const int* __restrict__ kqw, const void* __restrict__ ksc, const void* __restrict__ kmn,
    const int* __restrict__ vqw, const void* __restrict__ vsc, const void* __restrict__ vmn,
    const u16* __restrict__ qrb, const u16* __restrict__ kfullb, const u16* __restrict__ vfullT,
    const float2* __restrict__ ctab, const int* __restrict__ flagp,
    float* __restrict__ Opart, float* __restrict__ ml)
{
  bool isbf = (*flagp != 0);
  int bh = blockIdx.x, grp = blockIdx.y;
  int tid = threadIdx.x;

  __shared__ u16 Qs[32][136];                     // persistent
  __shared__ u16 KV[128][136];                    // K tile, then V^T tile
  __shared__ __align__(16) unsigned char uB[16896];
  u16 (*Pl)[136]    = (u16(*)[136])uB;            // 8704 B   (lifetime: D2..F)
  float (*Ssm)[132] = (float(*)[132])uB;          // 16896 B  (lifetime: C..D1)
  __shared__ float m_s[32], l_s[32], alpha_s[32];

  for (int u = tid; u < 512; u += 256) {
    int row = u >> 4, c8 = u & 15;
    *(uint4*)&Qs[row][c8 * 8] = *(const uint4*)&qrb[(bh * 32 + row) * 128 + c8 * 8];
  }
  if (tid < 32) { m_s[tid] = -INFINITY; l_s[tid] = 0.f; }

  int wv = tid >> 6, lane = tid & 63, lr = lane & 15, lq = lane >> 4;
  int mt = wv & 1, nh = wv >> 1;
  int row = tid >> 3, sub = tid & 7;
  f32x4 zf = {0.f, 0.f, 0.f, 0.f};
  f32x4 oacc[4];
  for (int nt = 0; nt < 4; nt++) oacc[nt] = zf;

  for (int j = 0; j < 8; j++) {
    int c = grp * 8 + j;
    bool fullc = (c == 31);
    int nk = fullc ? 64 : 128;
    __syncthreads();                               // sync0: prev Pl/KV reads done; Qs visible
    // ---- A: stage K chunk into KV[t][d] ----
    if (!fullc) {
      for (int jj = 0; jj < 8; jj++) {
        int task = tid + 256 * jj;
        int d = task & 127, tw = task >> 7;        // tw in [0,16)
        int gw = c * 16 + tw;
        int d2 = d ^ 64;
        unsigned w1 = (unsigned)kqw[(bh * 128 + d)  * 496 + gw];
        unsigned w2 = (unsigned)kqw[(bh * 128 + d2) * 496 + gw];
        int gq = gw >> 2;                          // t-group (32 t per group)
        float sc1 = ldf(ksc, (bh * 128 + d)  * 124 + gq, isbf);
        float m1  = ldf(kmn, (bh * 128 + d)  * 124 + gq, isbf);
        float sc2 = ldf(ksc, (bh * 128 + d2) * 124 + gq, isbf);
        float m2  = ldf(kmn, (bh * 128 + d2) * 124 + gq, isbf);
        int dm = d & 63;
        float sgn = (d < 64) ? -1.0f : 1.0f;
        int tl0 = tw * 8;
        for (int i = 0; i < 8; i++) {
          float v1 = (float)((w1 >> (4 * i)) & 15u) * sc1 + m1;
          float v2 = (float)((w2 >> (4 * i)) & 15u) * sc2 + m2;
          float2 cs = ctab[(c * 128 + tl0 + i) * 64 + dm];
          KV[tl0 + i][d] = f2bf(v1 * cs.x + sgn * (v2 * cs.y));
        }
      }
    } else {
      for (int u = tid; u < 1024; u += 256) {
        int r2 = u >> 4, c8 = u & 15;
        *(uint4*)&KV[r2][c8 * 8] = *(const uint4*)&kfullb[(bh * 64 + r2) * 128 + c8 * 8];
      }
      uint4 z = {0u, 0u, 0u, 0u};
      for (int u = tid; u < 1024; u += 256) {
        int r2 = u >> 4, c8 = u & 15;
        *(uint4*)&KV[64 + r2][c8 * 8] = z;
      }
    }
    __syncthreads();                               // sync1
    // ---- B: S = Q . K^T ----
    f32x4 sacc[4];
    for (int nt = 0; nt < 4; nt++) sacc[nt] = zf;
    for (int ks = 0; ks < 4; ks++) {
      bf16x8 af = *(const bf16x8*)&Qs[mt * 16 + lr][ks * 32 + lq * 8];
      for (int nt = 0; nt < 4; nt++) {
        bf16x8 bfr = *(const bf16x8*)&KV[nh * 64 + nt * 16 + lr][ks * 32 + lq * 8];
        sacc[nt] = MFMA16(af, bfr, sacc[nt]);
      }
    }
    // ---- C: spill S to Ssm ----
    for (int nt = 0; nt < 4; nt++)
      for (int r = 0; r < 4; r++)
        Ssm[mt * 16 + lq * 4 + r][nh * 64 + nt * 16 + lr] = sacc[nt][r];
    __syncthreads();                               // sync2
    // ---- D1: chunk softmax + online-merge (8 threads per row) ----
    float vals[16]; float mx = -INFINITY;
    for (int jj = 0; jj < 16; jj++) {
      int cc = sub * 16 + jj;
      float s = Ssm[row][cc] * 0.08838834764831845f;   // 1/sqrt(128)
      s = (cc < nk) ? s : -INFINITY;
      vals[jj] = s;
      mx = fmaxf(mx, s);
    }
    mx = fmaxf(mx, __shfl_xor(mx, 1));
    mx = fmaxf(mx, __shfl_xor(mx, 2));
    mx = fmaxf(mx, __shfl_xor(mx, 4));
    float m_old = m_s[row];                        // same-wave read before sub0 write
    float m_new = fmaxf(m_old, mx);
    float alpha = expf(m_old - m_new);             // 0 on first chunk
    u16 pb[16]; float sum = 0.f;
    for (int jj = 0; jj < 16; jj++) {
      float p = (sub * 16 + jj < nk) ? expf(vals[jj] - m_new) : 0.0f;
      u16 q = f2bf(p);
      pb[jj] = q;
      sum += b2f(q);
    }
    sum += __shfl_xor(sum, 1);
    sum += __shfl_xor(sum, 2);
    sum += __shfl_xor(sum, 4);
    if (sub == 0) {
      m_s[row] = m_new;
      l_s[row] = l_s[row] * alpha + sum;
      alpha_s[row] = alpha;
    }
    __syncthreads();                               // sync3: Ssm reads done, alpha_s ready
    // ---- D2: write P (overlays Ssm) ----
    for (int jj = 0; jj < 16; jj++) Pl[row][sub * 16 + jj] = pb[jj];
    // ---- E: stage V^T into KV[d][t] ----
    if (!fullc) {
      for (int jj = 0; jj < 8; jj++) {
        int task = tid + 256 * jj;
        int tl = task & 127, w = task >> 7;
        int t = c * 128 + tl;
        unsigned wd = (unsigned)vqw[(bh * 3968 + t) * 16 + w];
        int gq = w >> 2;
        float sc = ldf(vsc, (bh * 3968 + t) * 4 + gq, isbf);
        float mn = ldf(vmn, (bh * 3968 + t) * 4 + gq, isbf);
        int d0 = w * 8;
        for (int i = 0; i < 8; i++)
          KV[d0 + i][tl] = f2bf((float)((wd >> (4 * i)) & 15u) * sc + mn);
      }
    } else {
      for (int u = tid; u < 1024; u += 256) {
        int d = u >> 3, c8 = u & 7;
        *(uint4*)&KV[d][c8 * 8] = *(const uint4*)&vfullT[(bh * 128 + d) * 64 + c8 * 8];
      }
      uint4 z = {0u, 0u, 0u, 0u};
      for (int u = tid; u < 1024; u += 256) {
        int d = u >> 3, c8 = u & 7;
        *(uint4*)&KV[d][64 + c8 * 8] = z;
      }
    }
    __syncthreads();                               // sync4
    // ---- F: O = O*alpha + P . V ----
    f32x4 pv[4];
    for (int nt = 0; nt < 4; nt++) pv[nt] = zf;
    for (int ks = 0; ks < 4; ks++) {
      bf16x8 af = *(const bf16x8*)&Pl[mt * 16 + lr][ks * 32 + lq * 8];
      for (int nt = 0; nt < 4; nt++) {
        bf16x8 bfr = *(const bf16x8*)&KV[nh * 64 + nt * 16 + lr][ks * 32 + lq * 8];
        pv[nt] = MFMA16(af, bfr, pv[nt]);
      }
    }
    for (int r = 0; r < 4; r++) {
      float a = alpha_s[mt * 16 + lq * 4 + r];
      for (int nt = 0; nt < 4; nt++) oacc[nt][r] = oacc[nt][r] * a + pv[nt][r];
    }
  }

  __syncthreads();
  float* Ob = Opart + (size_t)((bh * 4 + grp) * 32) * 128;
  for (int nt = 0; nt < 4; nt++)
    for (int r = 0; r < 4; r++)
      Ob[(mt * 16 + lq * 4 + r) * 128 + nh * 64 + nt * 16 + lr] = oacc[nt][r];
  if (tid < 32) {
    ml[((bh * 4 + grp) * 32 + tid) * 2 + 0] = m_s[tid];
    ml[((bh * 4 + grp) * 32 + tid) * 2 + 1] = l_s[tid];
  }
}

// ---------------------------------------------------------------------------
// Combine 4 group partials per bh. Grid (64), 256 threads.
// ---------------------------------------------------------------------------
__global__ __launch_bounds__(256) void combine_kernel(
    const float* __restrict__ Opart, const float* __restrict__ ml, u16* __restrict__ attn_out)
{
  int bh = blockIdx.x, tid = threadIdx.x;
  __shared__ float Wg[4][32], Ls[32];
  if (tid < 32) {
    float M = -INFINITY;
    for (int g = 0; g < 4; g++)
      M = fmaxf(M, ml[((bh * 4 + g) * 32 + tid) * 2]);
    float L = 0.f;
    for (int g = 0; g < 4; g++) {
      float m = ml[((bh * 4 + g) * 32 + tid) * 2];
      float l = ml[((bh * 4 + g) * 32 + tid) * 2 + 1];
      float w = expf(m - M);
      Wg[g][tid] = w;
      L += l * w;
    }
    Ls[tid] = L;
  }
  __syncthreads();
  int row = tid >> 3, sub = tid & 7;
  int d0 = sub * 16;
  float acc[16];
  for (int k = 0; k < 16; k++) acc[k] = 0.f;
  for (int g = 0; g < 4; g++) {
    float w = Wg[g][row];
    const float* base = Opart + (size_t)((bh * 4 + g) * 32 + row) * 128 + d0;
    for (int k4 = 0; k4 < 4; k4++) {
      float4 v = *(const float4*)(base + k4 * 4);
      acc[k4 * 4 + 0] += w * v.x; acc[k4 * 4 + 1] += w * v.y;
      acc[k4 * 4 + 2] += w * v.z; acc[k4 * 4 + 3] += w * v.w;
    }
  }
  float inv = 1.0f / Ls[row];
  int b = bh >> 3, kvh = bh & 7, hg = row >> 3, qp = row & 7;
  u16* dst = attn_out + (size_t)(b * 8 + qp) * 4096 + (kvh * 4 + hg) * 128 + d0;
  for (int k = 0; k < 16; k++) dst[k] = f2bf(acc[k] * inv);
}

// ---------------------------------------------------------------------------
extern "C" void kernel_launch(void* const* d_in, const int* in_sizes, int n_in,
                              void* d_out, int out_size, void* d_ws, size_t ws_size,
                              hipStream_t stream)
{
  const void* hidden = d_in[0];
  const void* Wq  = d_in[1];
  const void* Wk  = d_in[2];
  const void* Wv  = d_in[3];
  const void* Wo  = d_in[4];
  const int*  kqw = (const int*)d_in[5];
  const void* ksc = d_in[6];
  const void* kmn = d_in[7];
  const void* kfp = d_in[8];
  const int*  vqw = (const int*)d_in[9];
  const void* vsc = d_in[10];
  const void* vmn = d_in[11];
  const void* vfp = d_in[12];

  char* ws = (char*)d_ws;
  int*    flag     = (int*)(ws);                    // 256 B
  float2* ctab     = (float2*)(ws + 256);           // 2,064,384
  u16*    Cqkv     = (u16*)(ws + 2064640);          //   786,432
  u16*    qrb      = (u16*)(ws + 2851072);          //   524,288
  u16*    kfullb   = (u16*)(ws + 3375360);          // 1,048,576
  u16*    vfullT   = (u16*)(ws + 4423936);          // 1,048,576
  u16*    attn_out = (u16*)(ws + 5472512);          //   524,288
  float*  Opart    = (float*)(ws + 5996800);        // 4,194,304
  float*  ml       = (float*)(ws + 10191104);       //    65,536   (total ~10.26 MB)

  detect_kernel<<<1, 256, 0, stream>>>((const u16*)hidden, flag);
  ctab_kernel<<<1008, 256, 0, stream>>>(ctab);
  proj_kernel<<<384, 256, 0, stream>>>(hidden, Wq, Wk, Wv, Cqkv, 4096, 1024, 6144, flag, 1, 0);
  prep_kernel<<<5120, 256, 0, stream>>>(Cqkv, kfp, vfp, ctab, flag, qrb, kfullb, vfullT);
  attn_kernel<<<dim3(64, 4), 256, 0, stream>>>(kqw, ksc, kmn, vqw, vsc, vmn,
                                               qrb, kfullb, vfullT, ctab, flag, Opart, ml);
  combine_kernel<<<64, 256, 0, stream>>>(Opart, ml, attn_out);
  proj_kernel<<<256, 256, 0, stream>>>(attn_out, Wo, Wo, Wo, d_out, 4096, 0, 4096, flag, 0, 1);
}

// Round 3
// 361.288 us; speedup vs baseline: 1.2929x; 1.2929x over previous
//
#include <hip/hip_runtime.h>

typedef unsigned short u16;
typedef short bf16x8 __attribute__((ext_vector_type(8)));
typedef float f32x4 __attribute__((ext_vector_type(4)));

__device__ __forceinline__ float b2f(u16 u) { return __uint_as_float(((unsigned)u) << 16); }
__device__ __forceinline__ u16 f2bf(float f) {
  unsigned u = __float_as_uint(f);
  u += 0x7fffu + ((u >> 16) & 1u);   // RNE
  return (u16)(u >> 16);
}

// dual-dtype scalar load: tensor is bf16 (u16) if isbf else f32
__device__ __forceinline__ float ldf(const void* p, int i, bool isbf) {
  return isbf ? b2f(((const u16*)p)[i]) : ((const float*)p)[i];
}
// dual-dtype 8-element load -> bf16 LDS
__device__ __forceinline__ void ld8(u16* dst, const void* p, int i, bool isbf) {
  if (isbf) {
    *(uint4*)dst = *(const uint4*)((const u16*)p + i);
  } else {
    float4 a = *(const float4*)((const float*)p + i);
    float4 b = *(const float4*)((const float*)p + i + 4);
    dst[0] = f2bf(a.x); dst[1] = f2bf(a.y); dst[2] = f2bf(a.z); dst[3] = f2bf(a.w);
    dst[4] = f2bf(b.x); dst[5] = f2bf(b.y); dst[6] = f2bf(b.z); dst[7] = f2bf(b.w);
  }
}

#define MFMA16(a, b, c) __builtin_amdgcn_mfma_f32_16x16x32_bf16((a), (b), (c), 0, 0, 0)

// ---------------------------------------------------------------------------
// dtype detector: bf16 vs f32 by exponent plausibility of first 4096 u16 words
// ---------------------------------------------------------------------------
__global__ __launch_bounds__(256) void detect_kernel(const u16* __restrict__ h, int* __restrict__ flag) {
  int tid = threadIdx.x;
  int cnt = 0;
  for (int i = tid; i < 4096; i += 256) {
    int e = (h[i] >> 7) & 0xFF;
    cnt += (e >= 116 && e <= 132) ? 1 : 0;   // |x| in [2^-11, 2^5]
  }
  __shared__ int sh[256];
  sh[tid] = cnt; __syncthreads();
  for (int s = 128; s > 0; s >>= 1) { if (tid < s) sh[tid] += sh[tid + s]; __syncthreads(); }
  if (tid == 0) flag[0] = (sh[0] >= 3100) ? 1 : 0;
}

// ---------------------------------------------------------------------------
// cos/sin table: ctab[t][dm], t in [0,4032), dm in [0,64)
// ---------------------------------------------------------------------------
__global__ __launch_bounds__(256) void ctab_kernel(float2* __restrict__ ctab) {
  int idx = blockIdx.x * 256 + threadIdx.x;       // 258048 exact
  int dm = idx & 63, t = idx >> 6;
  float f = exp2f(-(float)dm * (13.287712379549449f / 64.0f));
  float ang = (float)t * f;
  float s, c;
  sincosf(ang, &s, &c);
  ctab[idx] = make_float2(c, s);
}

// ---------------------------------------------------------------------------
// Split-K projection: out32[ks][64][ostride] partial = X[64][Kslice] . W^T
// grid (Ntot/16, 4); blockIdx.y = K-split of 1024. 8 k-iters per block.
// ---------------------------------------------------------------------------
__global__ __launch_bounds__(256) void proj_kernel(
    const void* __restrict__ X, const void* __restrict__ Wa,
    const void* __restrict__ Wb, const void* __restrict__ Wc,
    float* __restrict__ out32, int Na, int Nb, int ostride,
    const int* __restrict__ flagp, int x_dyn)
{
  bool fbf = (*flagp != 0);
  bool xbf = x_dyn ? fbf : true;
  int n0 = blockIdx.x * 16;
  int ks0 = blockIdx.y * 1024;
  const void* W; int wr0;
  if (n0 < Na)           { W = Wa; wr0 = n0; }
  else if (n0 < Na + Nb) { W = Wb; wr0 = n0 - Na; }
  else                   { W = Wc; wr0 = n0 - Na - Nb; }

  __shared__ u16 Xs[64][136];
  __shared__ u16 Ws[16][136];
  int tid = threadIdx.x;
  int wv = tid >> 6, lane = tid & 63, lr = lane & 15, lq = lane >> 4;
  f32x4 acc = {0.f, 0.f, 0.f, 0.f};

  for (int k0 = ks0; k0 < ks0 + 1024; k0 += 128) {
    __syncthreads();
    for (int u = tid; u < 1024; u += 256) {       // X tile 64x128
      int row = u >> 4, c8 = u & 15;
      ld8(&Xs[row][c8 * 8], X, row * 4096 + k0 + c8 * 8, xbf);
    }
    { int row = tid >> 4, c8 = tid & 15;          // W tile 16x128
      ld8(&Ws[row][c8 * 8], W, (wr0 + row) * 4096 + k0 + c8 * 8, fbf); }
    __syncthreads();
    for (int ks = 0; ks < 4; ks++) {
      bf16x8 af  = *(const bf16x8*)&Xs[wv * 16 + lr][ks * 32 + lq * 8];
      bf16x8 bfr = *(const bf16x8*)&Ws[lr][ks * 32 + lq * 8];
      acc = MFMA16(af, bfr, acc);
    }
  }
  float* outp = out32 + (size_t)blockIdx.y * 64 * ostride;
  for (int r = 0; r < 4; r++)
    outp[(wv * 16 + lq * 4 + r) * ostride + n0 + lr] = acc[r];
}

// sum the 4 K-split partials of the QKV projection (stride 64*6144 floats)
__device__ __forceinline__ float c4(const float* __restrict__ p, int i) {
  return p[i] + p[i + 393216] + p[i + 786432] + p[i + 1179648];
}

// ---------------------------------------------------------------------------
// Prep: RoPE'd Q [bh][32][128], RoPE'd full-K [bh][64][128], V_full^T [bh][128][64]
// ---------------------------------------------------------------------------
__global__ __launch_bounds__(256) void prep_kernel(
    const float* __restrict__ Cq32, const void* __restrict__ kfp, const void* __restrict__ vfp,
    const float2* __restrict__ ctab, const int* __restrict__ flagp,
    u16* __restrict__ qrb, u16* __restrict__ kfullb, u16* __restrict__ vfullT)
{
  bool isbf = (*flagp != 0);
  int idx = blockIdx.x * 256 + threadIdx.x;       // 1,310,720 exact
  if (idx < 262144) {                              // qr
    int d = idx & 127, row = (idx >> 7) & 31, bh = idx >> 12;
    int b = bh >> 3, kvh = bh & 7, g = row >> 3, qp = row & 7;
    int tok = b * 8 + qp, h = kvh * 4 + g;
    float x  = c4(Cq32, tok * 6144 + h * 128 + d);
    float x2 = c4(Cq32, tok * 6144 + h * 128 + (d ^ 64));
    float2 cs = ctab[(4024 + qp) * 64 + (d & 63)];
    float sgn = (d < 64) ? -1.f : 1.f;
    qrb[idx] = f2bf(x * cs.x + sgn * (x2 * cs.y));
  } else if (idx < 786432) {                       // k_full roped, pos = 3968+t
    int j = idx - 262144;
    int d = j & 127, t = (j >> 7) & 63, bh = j >> 13;
    int b = bh >> 3, kvh = bh & 7;
    float x, x2;
    if (t < 56) {
      x  = ldf(kfp, (bh * 56 + t) * 128 + d, isbf);
      x2 = ldf(kfp, (bh * 56 + t) * 128 + (d ^ 64), isbf);
    } else {
      int tok = b * 8 + (t - 56);
      x  = c4(Cq32, tok * 6144 + 4096 + kvh * 128 + d);
      x2 = c4(Cq32, tok * 6144 + 4096 + kvh * 128 + (d ^ 64));
    }
    float2 cs = ctab[(3968 + t) * 64 + (d & 63)];
    float sgn = (d < 64) ? -1.f : 1.f;
    kfullb[j] = f2bf(x * cs.x + sgn * (x2 * cs.y));
  } else {                                         // v_full transposed [bh][d][t]
    int j = idx - 786432;
    int t = j & 63, d = (j >> 6) & 127, bh = j >> 13;
    int b = bh >> 3, kvh = bh & 7;
    float x;
    if (t < 56) x = ldf(vfp, (bh * 56 + t) * 128 + d, isbf);
    else        x = c4(Cq32, (b * 8 + t - 56) * 6144 + 5120 + kvh * 128 + d);
    vfullT[j] = f2bf(x);
  }
}

// ---------------------------------------------------------------------------
// Online-flash attention, 2 chunks per block. Grid (64 bh, 16 grp).
// Chunks 0..30: 128 quantized keys (dequant+RoPE). Chunk 31: 64 full keys.
// Q fragments in registers; LDS = KV(34816) + union{Pl|Ssm}(16896) + 384
//  = 52.1 KB -> 3 blocks/CU.
// ---------------------------------------------------------------------------
__global__ __launch_bounds__(256) void attn_kernel(
    const int* __restrict__ kqw, const void* __restrict__ ksc, const void* __restrict__ kmn,
    const int* __restrict__ vqw, const void* __restrict__ vsc, const void* __restrict__ vmn,
    const u16* __restrict__ qrb, const u16* __restrict__ kfullb, const u16* __restrict__ vfullT,
    const float2* __restrict__ ctab, const int* __restrict__ flagp,
    u16* __restrict__ Opart, float* __restrict__ ml)
{
  bool isbf = (*flagp != 0);
  int bh = blockIdx.x, grp = blockIdx.y;
  int tid = threadIdx.x;

  __shared__ u16 KV[128][136];                    // K tile, then V^T tile
  __shared__ __align__(16) unsigned char uB[16896];
  u16 (*Pl)[136]    = (u16(*)[136])uB;            // bf16 P   (lifetime: D2..F)
  float (*Ssm)[132] = (float(*)[132])uB;          // f32 S    (lifetime: C..D1)
  __shared__ float m_s[32], l_s[32], alpha_s[32];

  int wv = tid >> 6, lane = tid & 63, lr = lane & 15, lq = lane >> 4;
  int mt = wv & 1, nh = wv >> 1;
  int row = tid >> 3, sub = tid & 7;

  // Q fragments in registers (A-layout: m = lane&15, k = lq*8 + j within ks-block)
  bf16x8 qa[4];
  for (int ks = 0; ks < 4; ks++)
    qa[ks] = *(const bf16x8*)&qrb[(bh * 32 + mt * 16 + lr) * 128 + ks * 32 + lq * 8];

  if (tid < 32) { m_s[tid] = -INFINITY; l_s[tid] = 0.f; }

  f32x4 zf = {0.f, 0.f, 0.f, 0.f};
  f32x4 oacc[4];
  for (int nt = 0; nt < 4; nt++) oacc[nt] = zf;

  for (int j = 0; j < 2; j++) {
    int c = grp * 2 + j;
    bool fullc = (c == 31);
    int nk = fullc ? 64 : 128;
    __syncthreads();                               // sync0: prior Pl/KV reads done; m_s init visible
    // ---- A: stage K chunk into KV[t][d] ----
    if (!fullc) {
      for (int jj = 0; jj < 8; jj++) {
        int task = tid + 256 * jj;
        int d = task & 127, tw = task >> 7;        // tw in [0,16)
        int gw = c * 16 + tw;
        int d2 = d ^ 64;
        unsigned w1 = (unsigned)kqw[(bh * 128 + d)  * 496 + gw];
        unsigned w2 = (unsigned)kqw[(bh * 128 + d2) * 496 + gw];
        int gq = gw >> 2;                          // t-group (32 t per group)
        float sc1 = ldf(ksc, (bh * 128 + d)  * 124 + gq, isbf);
        float m1  = ldf(kmn, (bh * 128 + d)  * 124 + gq, isbf);
        float sc2 = ldf(ksc, (bh * 128 + d2) * 124 + gq, isbf);
        float m2  = ldf(kmn, (bh * 128 + d2) * 124 + gq, isbf);
        int dm = d & 63;
        float sgn = (d < 64) ? -1.0f : 1.0f;
        int tl0 = tw * 8;
        for (int i = 0; i < 8; i++) {
          float v1 = (float)((w1 >> (4 * i)) & 15u) * sc1 + m1;
          float v2 = (float)((w2 >> (4 * i)) & 15u) * sc2 + m2;
          float2 cs = ctab[(c * 128 + tl0 + i) * 64 + dm];
          KV[tl0 + i][d] = f2bf(v1 * cs.x + sgn * (v2 * cs.y));
        }
      }
    } else {
      for (int u = tid; u < 1024; u += 256) {
        int r2 = u >> 4, c8 = u & 15;
        *(uint4*)&KV[r2][c8 * 8] = *(const uint4*)&kfullb[(bh * 64 + r2) * 128 + c8 * 8];
      }
      uint4 z = {0u, 0u, 0u, 0u};
      for (int u = tid; u < 1024; u += 256) {
        int r2 = u >> 4, c8 = u & 15;
        *(uint4*)&KV[64 + r2][c8 * 8] = z;
      }
    }
    __syncthreads();                               // sync1
    // ---- B: S = Q . K^T ----
    f32x4 sacc[4];
    for (int nt = 0; nt < 4; nt++) sacc[nt] = zf;
    for (int ks = 0; ks < 4; ks++) {
      for (int nt = 0; nt < 4; nt++) {
        bf16x8 bfr = *(const bf16x8*)&KV[nh * 64 + nt * 16 + lr][ks * 32 + lq * 8];
        sacc[nt] = MFMA16(qa[ks], bfr, sacc[nt]);
      }
    }
    // ---- C: spill S to Ssm ----
    for (int nt = 0; nt < 4; nt++)
      for (int r = 0; r < 4; r++)
        Ssm[mt * 16 + lq * 4 + r][nh * 64 + nt * 16 + lr] = sacc[nt][r];
    __syncthreads();                               // sync2
    // ---- D1: chunk softmax + online-merge (8 threads per row) ----
    float vals[16]; float mx = -INFINITY;
    for (int jj = 0; jj < 16; jj++) {
      int cc = sub * 16 + jj;
      float s = Ssm[row][cc] * 0.08838834764831845f;   // 1/sqrt(128)
      s = (cc < nk) ? s : -INFINITY;
      vals[jj] = s;
      mx = fmaxf(mx, s);
    }
    mx = fmaxf(mx, __shfl_xor(mx, 1));
    mx = fmaxf(mx, __shfl_xor(mx, 2));
    mx = fmaxf(mx, __shfl_xor(mx, 4));
    float m_old = m_s[row];                        // same-wave read precedes sub0 write
    float m_new = fmaxf(m_old, mx);
    float alpha = expf(m_old - m_new);             // 0 on first chunk
    u16 pb[16]; float sum = 0.f;
    for (int jj = 0; jj < 16; jj++) {
      float p = (sub * 16 + jj < nk) ? expf(vals[jj] - m_new) : 0.0f;
      u16 q = f2bf(p);
      pb[jj] = q;
      sum += b2f(q);
    }
    sum += __shfl_xor(sum, 1);
    sum += __shfl_xor(sum, 2);
    sum += __shfl_xor(sum, 4);
    if (sub == 0) {
      m_s[row] = m_new;
      l_s[row] = l_s[row] * alpha + sum;
      alpha_s[row] = alpha;
    }
    __syncthreads();                               // sync3: Ssm reads done, alpha_s ready
    // ---- D2: write P (overlays Ssm) ----
    for (int jj = 0; jj < 16; jj++) Pl[row][sub * 16 + jj] = pb[jj];
    // ---- E: stage V^T into KV[d][t] ----
    if (!fullc) {
      for (int jj = 0; jj < 8; jj++) {
        int task = tid + 256 * jj;
        int tl = task & 127, w = task >> 7;
        int t = c * 128 + tl;
        unsigned wd = (unsigned)vqw[(bh * 3968 + t) * 16 + w];
        int gq = w >> 2;
        float sc = ldf(vsc, (bh * 3968 + t) * 4 + gq, isbf);
        float mn = ldf(vmn, (bh * 3968 + t) * 4 + gq, isbf);
        int d0 = w * 8;
        for (int i = 0; i < 8; i++)
          KV[d0 + i][tl] = f2bf((float)((wd >> (4 * i)) & 15u) * sc + mn);
      }
    } else {
      for (int u = tid; u < 1024; u += 256) {
        int d = u >> 3, c8 = u & 7;
        *(uint4*)&KV[d][c8 * 8] = *(const uint4*)&vfullT[(bh * 128 + d) * 64 + c8 * 8];
      }
      uint4 z = {0u, 0u, 0u, 0u};
      for (int u = tid; u < 1024; u += 256) {
        int d = u >> 3, c8 = u & 7;
        *(uint4*)&KV[d][64 + c8 * 8] = z;
      }
    }
    __syncthreads();                               // sync4
    // ---- F: O = O*alpha + P . V ----
    f32x4 pv[4];
    for (int nt = 0; nt < 4; nt++) pv[nt] = zf;
    for (int ks = 0; ks < 4; ks++) {
      bf16x8 af = *(const bf16x8*)&Pl[mt * 16 + lr][ks * 32 + lq * 8];
      for (int nt = 0; nt < 4; nt++) {
        bf16x8 bfr = *(const bf16x8*)&KV[nh * 64 + nt * 16 + lr][ks * 32 + lq * 8];
        pv[nt] = MFMA16(af, bfr, pv[nt]);
      }
    }
    for (int r = 0; r < 4; r++) {
      float a = alpha_s[mt * 16 + lq * 4 + r];
      for (int nt = 0; nt < 4; nt++) oacc[nt][r] = oacc[nt][r] * a + pv[nt][r];
    }
  }

  __syncthreads();
  u16* Ob = Opart + (size_t)((bh * 16 + grp) * 32) * 128;
  for (int nt = 0; nt < 4; nt++)
    for (int r = 0; r < 4; r++)
      Ob[(mt * 16 + lq * 4 + r) * 128 + nh * 64 + nt * 16 + lr] = f2bf(oacc[nt][r]);
  if (tid < 32) {
    ml[((bh * 16 + grp) * 32 + tid) * 2 + 0] = m_s[tid];
    ml[((bh * 16 + grp) * 32 + tid) * 2 + 1] = l_s[tid];
  }
}

// ---------------------------------------------------------------------------
// Combine 16 group partials per bh. Grid (64), 256 threads.
// ---------------------------------------------------------------------------
__global__ __launch_bounds__(256) void combine_kernel(
    const u16* __restrict__ Opart, const float* __restrict__ ml, u16* __restrict__ attn_out)
{
  int bh = blockIdx.x, tid = threadIdx.x;
  __shared__ float Wg[16][32], Ls[32];
  if (tid < 32) {
    float M = -INFINITY;
    for (int g = 0; g < 16; g++)
      M = fmaxf(M, ml[((bh * 16 + g) * 32 + tid) * 2]);
    float L = 0.f;
    for (int g = 0; g < 16; g++) {
      float m = ml[((bh * 16 + g) * 32 + tid) * 2];
      float l = ml[((bh * 16 + g) * 32 + tid) * 2 + 1];
      float w = expf(m - M);
      Wg[g][tid] = w;
      L += l * w;
    }
    Ls[tid] = L;
  }
  __syncthreads();
  int row = tid >> 3, sub = tid & 7;
  int d0 = sub * 16;
  float acc[16];
  for (int k = 0; k < 16; k++) acc[k] = 0.f;
  for (int g = 0; g < 16; g++) {
    float w = Wg[g][row];
    const u16* base = Opart + (size_t)((bh * 16 + g) * 32 + row) * 128 + d0;
    for (int k8 = 0; k8 < 2; k8++) {
      uint4 v = *(const uint4*)(base + k8 * 8);
      const u16* h = (const u16*)&v;
      for (int k = 0; k < 8; k++) acc[k8 * 8 + k] += w * b2f(h[k]);
    }
  }
  float inv = 1.0f / Ls[row];
  int b = bh >> 3, kvh = bh & 7, hg = row >> 3, qp = row & 7;
  u16* dst = attn_out + (size_t)(b * 8 + qp) * 4096 + (kvh * 4 + hg) * 128 + d0;
  for (int k = 0; k < 16; k++) dst[k] = f2bf(acc[k] * inv);
}

// ---------------------------------------------------------------------------
// Sum 4 Wo K-split partials, emit final output in detected dtype.
// ---------------------------------------------------------------------------
__global__ __launch_bounds__(256) void cast_kernel(
    const float* __restrict__ O32, const int* __restrict__ flagp, void* __restrict__ out)
{
  int i = blockIdx.x * 256 + threadIdx.x;          // 262144 exact
  float v = O32[i] + O32[i + 262144] + O32[i + 524288] + O32[i + 786432];
  if (*flagp) ((u16*)out)[i] = f2bf(v);
  else        ((float*)out)[i] = v;
}

// ---------------------------------------------------------------------------
extern "C" void kernel_launch(void* const* d_in, const int* in_sizes, int n_in,
                              void* d_out, int out_size, void* d_ws, size_t ws_size,
                              hipStream_t stream)
{
  const void* hidden = d_in[0];
  const void* Wq  = d_in[1];
  const void* Wk  = d_in[2];
  const void* Wv  = d_in[3];
  const void* Wo  = d_in[4];
  const int*  kqw = (const int*)d_in[5];
  const void* ksc = d_in[6];
  const void* kmn = d_in[7];
  const void* kfp = d_in[8];
  const int*  vqw = (const int*)d_in[9];
  const void* vsc = d_in[10];
  const void* vmn = d_in[11];
  const void* vfp = d_in[12];

  char* ws = (char*)d_ws;
  int*    flag     = (int*)(ws);                    //       256
  float2* ctab     = (float2*)(ws + 256);           // 2,064,384
  float*  Cq32     = (float*)(ws + 2064640);        // 6,291,456 (4 K-split partials)
  float*  O32      = Cq32;                          // overlay: lifetime disjoint (4,194,304)
  u16*    qrb      = (u16*)(ws + 8356096);          //   524,288
  u16*    attn_out = qrb;                           // overlay: qrb dead after attn
  u16*    kfullb   = (u16*)(ws + 8880384);          // 1,048,576
  u16*    vfullT   = (u16*)(ws + 9928960);          // 1,048,576
  u16*    Opart    = (u16*)(ws + 10977536);         // 8,388,608 (bf16)
  float*  ml       = (float*)(ws + 19366144);       //   524,288  -> total 19,890,432

  detect_kernel<<<1, 256, 0, stream>>>((const u16*)hidden, flag);
  ctab_kernel<<<1008, 256, 0, stream>>>(ctab);
  proj_kernel<<<dim3(384, 4), 256, 0, stream>>>(hidden, Wq, Wk, Wv, Cq32, 4096, 1024, 6144, flag, 1);
  prep_kernel<<<5120, 256, 0, stream>>>(Cq32, kfp, vfp, ctab, flag, qrb, kfullb, vfullT);
  attn_kernel<<<dim3(64, 16), 256, 0, stream>>>(kqw, ksc, kmn, vqw, vsc, vmn,
                                                qrb, kfullb, vfullT, ctab, flag, Opart, ml);
  combine_kernel<<<64, 256, 0, stream>>>(Opart, ml, attn_out);
  proj_kernel<<<dim3(256, 4), 256, 0, stream>>>(attn_out, Wo, Wo, Wo, O32, 4096, 0, 4096, flag, 0);
  cast_kernel<<<1024, 256, 0, stream>>>(O32, flag, d_out);
}